// Round 3
// baseline (5535.186 us; speedup 1.0000x reference)
//
#include <hip/hip_runtime.h>
#include <math.h>

// Problem constants: B=512, T=2048, D=10, H=20
#define BB 512
#define TT 2048
#define DD 10
#define HH 20
#define BH (BB*HH)          // 10240 elements per timestep

// ws layout (word indices from base)
#define WS_AMAX     0
#define WS_PROD_XWI 4
#define WS_INV_SX   5
#define WS_S_H0     6
#define WS_INV_SH0  7
#define WS_S_WH     8
#define WS_BQ       16
#define WS_WIP      40
#define WS_WHP      104
#define WS_XW_OFF   4096     // byte offset of xW / out_t buffer: [T][B][H] floats (84 MB)

// LDS-only barrier: never drains vmcnt (prefetch loads / output stores stay in flight)
#define BAR() asm volatile("s_waitcnt lgkmcnt(0)\n\ts_barrier" ::: "memory")

__device__ __forceinline__ int dot4(int a, int b, int c) {
    return __builtin_amdgcn_sdot4(a, b, c, false);
}

// scale = exp2(ceil(log2(max(m,1e-10))))/128 via exponent bits (exact, branchless)
__device__ __forceinline__ void p2s(float m, float* s, float* is) {
    m = fmaxf(m, 1e-10f);
    unsigned u = __float_as_uint(m);
    int k = (int)(u >> 23) - 127 + ((u & 0x7fffffu) ? 1 : 0);  // ceil(log2(m))
    *s  = __uint_as_float((unsigned)(k + 120) << 23);           // 2^(k-7)
    *is = __uint_as_float((unsigned)(134 - k) << 23);           // 2^(7-k)
}

__device__ __forceinline__ float fmed3(float a, float b, float c) {
    return __builtin_amdgcn_fmed3f(a, b, c);
}

__device__ __forceinline__ int qlevel(float v, float inv) {
    return (int)fmed3(rintf(v * inv), -128.f, 127.f);
}

__device__ __forceinline__ int pack4(int a, int b, int c, int d) {
    return (a & 255) | ((b & 255) << 8) | ((c & 255) << 16) | ((d & 255) << 24);
}

// monotone float<->uint encoding: order-preserving for all finite floats
__device__ __forceinline__ unsigned fenc(float x) {
    unsigned u = __float_as_uint(x);
    return u ^ (unsigned)(((int)u >> 31) | 0x80000000);
}
__device__ __forceinline__ float fdec(unsigned e) {
    unsigned mask = (~(unsigned)((int)e >> 31)) | 0x80000000u;
    return __uint_as_float(e ^ mask);
}

// wave64 umax via DPP (VALU only, no LDS): lane63 holds the full max
__device__ __forceinline__ unsigned wave_umax(unsigned m) {
    unsigned t;
    t = (unsigned)__builtin_amdgcn_update_dpp(0, (int)m, 0x111, 0xf, 0xf, true); m = m > t ? m : t; // shr1
    t = (unsigned)__builtin_amdgcn_update_dpp(0, (int)m, 0x112, 0xf, 0xf, true); m = m > t ? m : t; // shr2
    t = (unsigned)__builtin_amdgcn_update_dpp(0, (int)m, 0x114, 0xf, 0xf, true); m = m > t ? m : t; // shr4
    t = (unsigned)__builtin_amdgcn_update_dpp(0, (int)m, 0x118, 0xf, 0xf, true); m = m > t ? m : t; // shr8
    t = (unsigned)__builtin_amdgcn_update_dpp(0, (int)m, 0x142, 0xa, 0xf, true); m = m > t ? m : t; // bcast15 -> rows 1,3
    t = (unsigned)__builtin_amdgcn_update_dpp(0, (int)m, 0x143, 0xc, 0xf, true); m = m > t ? m : t; // bcast31 -> rows 2,3
    return m;
}

// umax over each 16-lane row (cyclic windows): every lane gets the row max
__device__ __forceinline__ unsigned row_umax(unsigned m) {
    unsigned t;
    t = (unsigned)__builtin_amdgcn_update_dpp(0, (int)m, 0x121, 0xf, 0xf, true); m = m > t ? m : t; // ror1
    t = (unsigned)__builtin_amdgcn_update_dpp(0, (int)m, 0x122, 0xf, 0xf, true); m = m > t ? m : t; // ror2
    t = (unsigned)__builtin_amdgcn_update_dpp(0, (int)m, 0x124, 0xf, 0xf, true); m = m > t ? m : t; // ror4
    t = (unsigned)__builtin_amdgcn_update_dpp(0, (int)m, 0x128, 0xf, 0xf, true); m = m > t ? m : t; // ror8
    return m;
}

// pair (lanes 2k,2k+1) h-level merge: 3 quad_perm DPP + byte splices -> hd[5]
__device__ __forceinline__ void mk_hd(int PA, int PB, int PC, bool isLo, int* hd) {
    int QA = __builtin_amdgcn_update_dpp(0, PA, 0xB1, 0xf, 0xf, true); // quad_perm [1,0,3,2]
    int QB = __builtin_amdgcn_update_dpp(0, PB, 0xB1, 0xf, 0xf, true);
    int QC = __builtin_amdgcn_update_dpp(0, PC, 0xB1, 0xf, 0xf, true);
    int XA = isLo ? PA : QA, XB = isLo ? PB : QB, XC = isLo ? PC : QC;
    int YA = isLo ? QA : PA, YB = isLo ? QB : PB, YC = isLo ? QC : PC;
    hd[0] = XA; hd[1] = XB;
    hd[2] = (XC & 0xFFFF) | (YA << 16);
    hd[3] = (int)((unsigned)YA >> 16) | (YB << 16);
    hd[4] = (int)((unsigned)YB >> 16) | (YC << 16);
}

// ---------------- kernel 1: maxabs(x) grid reduction -------------------------
__global__ void k_amax(const float* __restrict__ x, int n4, unsigned* amax) {
    int g = blockIdx.x * blockDim.x + threadIdx.x;
    int stride = gridDim.x * blockDim.x;
    const float4* xv = (const float4*)x;
    float m = 0.f;
    for (int i = g; i < n4; i += stride) {
        float4 v = xv[i];
        m = fmaxf(m, fmaxf(fmaxf(fabsf(v.x), fabsf(v.y)), fmaxf(fabsf(v.z), fabsf(v.w))));
    }
#pragma unroll
    for (int off = 32; off; off >>= 1) m = fmaxf(m, __shfl_xor(m, off, 64));
    if ((threadIdx.x & 63) == 0) atomicMax(amax, __float_as_uint(m));
}

// ---------------- kernel 2: scales + weight quant/pack -----------------------
__device__ float bmaxabs(const float* p, int n, float* red, int tid) {
    float m = 0.f;
    for (int i = tid; i < n; i += 256) m = fmaxf(m, fabsf(p[i]));
    red[tid] = m; __syncthreads();
    for (int s = 128; s; s >>= 1) {
        if (tid < s) red[tid] = fmaxf(red[tid], red[tid + s]);
        __syncthreads();
    }
    m = red[0]; __syncthreads();
    return m;
}

__global__ void k_prep(const float* __restrict__ Wi, const float* __restrict__ Wh,
                       const float* __restrict__ bias, const float* __restrict__ h0,
                       float* wsf, int* wsi) {
    __shared__ float red[256];
    __shared__ float hdr[4];
    int tid = threadIdx.x;
    float mwi = bmaxabs(Wi, HH * DD, red, tid);
    float mwh = bmaxabs(Wh, HH * HH, red, tid);
    float mb  = bmaxabs(bias, HH, red, tid);
    float mh0 = bmaxabs(h0, BH, red, tid);
    if (tid == 0) {
        float mx = __uint_as_float(((unsigned*)wsf)[WS_AMAX]);
        float sx, isx, swi, iswi, swh, iswh, sb, isb, sh0, ish0;
        p2s(mx,  &sx,  &isx);
        p2s(mwi, &swi, &iswi);
        p2s(mwh, &swh, &iswh);
        p2s(mb,  &sb,  &isb);
        p2s(mh0, &sh0, &ish0);
        wsf[WS_PROD_XWI] = sx * swi;
        wsf[WS_INV_SX]   = isx;
        wsf[WS_S_H0]     = sh0;
        wsf[WS_INV_SH0]  = ish0;
        wsf[WS_S_WH]     = swh;
        hdr[0] = iswi; hdr[1] = iswh; hdr[2] = sb; hdr[3] = isb;
    }
    __syncthreads();
    if (tid < HH) {
        float iswi = hdr[0], iswh = hdr[1], sb = hdr[2], isb = hdr[3];
        int lv[20];
#pragma unroll
        for (int d = 0; d < DD; ++d) lv[d] = qlevel(Wi[tid * DD + d], iswi);
        lv[10] = 0; lv[11] = 0;
#pragma unroll
        for (int k = 0; k < 3; ++k)
            wsi[WS_WIP + tid * 3 + k] = pack4(lv[4*k], lv[4*k+1], lv[4*k+2], lv[4*k+3]);
#pragma unroll
        for (int k = 0; k < HH; ++k) lv[k] = qlevel(Wh[tid * HH + k], iswh);
#pragma unroll
        for (int k = 0; k < 5; ++k)
            wsi[WS_WHP + tid * 5 + k] = pack4(lv[4*k], lv[4*k+1], lv[4*k+2], lv[4*k+3]);
        wsf[WS_BQ + tid] = (float)qlevel(bias[tid], isb) * sb;
    }
}

// ---------------- kernel 3: xW[t][b][j] = quant(x)·Wi_q + bq -----------------
__global__ __launch_bounds__(256) void k_xw(const float* __restrict__ x,
                                            const float* __restrict__ wsf,
                                            const int* __restrict__ wsi,
                                            float* __restrict__ xw) {
    int g = blockIdx.x * 256 + threadIdx.x;
    int b = g & (BB - 1);
    int t = g >> 9;
    float isx  = wsf[WS_INV_SX];
    float prod = wsf[WS_PROD_XWI];
    const float2* xp = (const float2*)(x + ((size_t)b * TT + t) * DD);
    float xv[10];
#pragma unroll
    for (int k = 0; k < 5; ++k) { float2 v = xp[k]; xv[2*k] = v.x; xv[2*k+1] = v.y; }
    int lv[12];
#pragma unroll
    for (int d = 0; d < DD; ++d) lv[d] = qlevel(xv[d], isx);
    lv[10] = 0; lv[11] = 0;
    int xpk[3];
#pragma unroll
    for (int k = 0; k < 3; ++k) xpk[k] = pack4(lv[4*k], lv[4*k+1], lv[4*k+2], lv[4*k+3]);
    float res[20];
#pragma unroll
    for (int j = 0; j < HH; ++j) {
        int ai = 0;
#pragma unroll
        for (int k = 0; k < 3; ++k) ai = dot4(xpk[k], wsi[WS_WIP + j * 3 + k], ai);
        res[j] = (float)ai * prod + wsf[WS_BQ + j];
    }
    float4* op = (float4*)(xw + (size_t)t * BH + b * HH);
#pragma unroll
    for (int k = 0; k < 5; ++k)
        op[k] = make_float4(res[4*k], res[4*k+1], res[4*k+2], res[4*k+3]);
}

// ---------------- kernel 4: serial recurrence, 1 workgroup -------------------
// thread = (b, jhalf). All cross-lane traffic via DPP (VALU). Per step:
// dot4 matmul -> fold -> monotone-enc DPP wave max -> lane63 ds_write -> B1 ->
// all threads: broadcast read + row_ror DPP reduce + redundant scale math
// (waves 0-3 also build exact-tanhf LUT) -> B2 -> LUT gather -> store + DPP
// pair exchange. 2 LDS-only barriers, ~12 LDS ops/thread-step.
__global__ __launch_bounds__(1024) void k_rnn(const float* __restrict__ h0,
                                              const float* __restrict__ wsf,
                                              const int* __restrict__ wsi,
                                              float* __restrict__ xw) {
    __shared__ uint2 wred[16];
    __shared__ int lut[256];
    const int tid = threadIdx.x;
    const int b = tid >> 1;
    const int jb = (tid & 1) * 10;
    const bool isLo = (tid & 1) == 0;
    const float s_wh = wsf[WS_S_WH];
    float sprod = wsf[WS_S_H0] * s_wh;

    int whp[50];
#pragma unroll
    for (int jj = 0; jj < 10; ++jj)
#pragma unroll
        for (int k = 0; k < 5; ++k)
            whp[jj * 5 + k] = wsi[WS_WHP + (jb + jj) * 5 + k];

    int hd[5];
    {   // h0 -> levels -> pack -> pair exchange
        float ish0 = wsf[WS_INV_SH0];
        const float2* hp = (const float2*)(h0 + b * HH + jb);
        int lv[10];
#pragma unroll
        for (int k = 0; k < 5; ++k) {
            float2 v = hp[k];
            lv[2*k]   = qlevel(v.x, ish0);
            lv[2*k+1] = qlevel(v.y, ish0);
        }
        mk_hd(pack4(lv[0], lv[1], lv[2], lv[3]),
              pack4(lv[4], lv[5], lv[6], lv[7]),
              (lv[8] & 255) | ((lv[9] & 255) << 8), isLo, hd);
    }
    float xwA[10];
    {
        const float2* p = (const float2*)(xw + b * HH + jb);
#pragma unroll
        for (int k = 0; k < 5; ++k) { float2 v = p[k]; xwA[2*k] = v.x; xwA[2*k+1] = v.y; }
    }
    const float2* pf = (const float2*)(xw + (size_t)BH + b * HH + jb);  // row t+1
    float2*       po = (float2*)(xw + b * HH + jb);                      // row t

    for (int t = 0; t < TT; ++t) {
        float xwB[10];
        if (t + 1 < TT) {   // wave-uniform branch; loads stay in flight across barriers
#pragma unroll
            for (int k = 0; k < 5; ++k) { float2 v = pf[k]; xwB[2*k] = v.x; xwB[2*k+1] = v.y; }
        }
        float acc[10];
#pragma unroll
        for (int jj = 0; jj < 10; ++jj) {
            int ai = 0;
#pragma unroll
            for (int k = 0; k < 5; ++k) ai = dot4(hd[k], whp[jj * 5 + k], ai);
            acc[jj] = fmaf((float)ai, sprod, xwA[jj]);   // exact: |ai| < 2^24, pow2 scale
        }
        // fold 10 -> (max, min), then monotone-uint DPP wave reduce
        float mx = acc[0], mn = acc[0];
#pragma unroll
        for (int jj = 1; jj < 10; ++jj) { mx = fmaxf(mx, acc[jj]); mn = fminf(mn, acc[jj]); }
        unsigned ea = wave_umax(fenc(mx));    // max(acc)
        unsigned eb = wave_umax(fenc(-mn));   // max(-acc)
        if ((tid & 63) == 63) wred[tid >> 6] = make_uint2(ea, eb);
        BAR();   // B1
        uint2 wp = wred[tid & 15];            // broadcast-friendly, conflict-free
        float ma = fdec(row_umax(wp.x));      // global max(acc)
        float nm = fdec(row_umax(wp.y));      // global max(-acc)
        float sa, isa; p2s(fmaxf(ma, nm), &sa, &isa);
        float lp = fmed3(rintf(ma * isa), -128.f, 127.f);
        float ln = fmed3(rintf(-nm * isa), -128.f, 127.f);
        float mlvl = fmaxf(fabsf(lp), fabsf(ln));   // max |acc_q| (clip asym: |-128| ok)
        float mh = tanhf(mlvl * sa);                // max |h_new| (tanh monotone)
        float sh, ish; p2s(mh, &sh, &ish);
        sprod = sh * s_wh;
        if (tid < 256) {   // exact LUT: acc level -> h level (waves 0-3, parallel w/ others)
            float tq = tanhf((float)(tid - 128) * sa);
            lut[tid] = (int)fmed3(rintf(tq * ish), -128.f, 127.f);
        }
        BAR();   // B2
        int ql[10];
#pragma unroll
        for (int jj = 0; jj < 10; ++jj) {
            int qi = (int)fmed3(rintf(acc[jj] * isa), -128.f, 127.f);
            ql[jj] = lut[qi + 128];
        }
#pragma unroll
        for (int k = 0; k < 5; ++k)   // out[t][b][j] = level*sh (fire-and-forget)
            po[k] = make_float2((float)ql[2*k] * sh, (float)ql[2*k+1] * sh);
        mk_hd(pack4(ql[0], ql[1], ql[2], ql[3]),
              pack4(ql[4], ql[5], ql[6], ql[7]),
              (ql[8] & 255) | ((ql[9] & 255) << 8), isLo, hd);
#pragma unroll
        for (int jj = 0; jj < 10; ++jj) xwA[jj] = xwB[jj];
        pf += BH / 2;
        po += BH / 2;
    }
}

// ---------------- kernel 5: transpose [T][B][H] -> [B][T][H] -----------------
__global__ __launch_bounds__(256) void k_tr(const float* __restrict__ src, float* __restrict__ out) {
    __shared__ float tile[16 * 16 * HH];   // 20 KB
    int t0 = blockIdx.x * 16, b0 = blockIdx.y * 16;
    for (int i = threadIdx.x; i < 16 * 16 * HH; i += 256) {
        int r = i / (16 * HH), c = i % (16 * HH);
        tile[i] = src[(size_t)(t0 + r) * BH + b0 * HH + c];
    }
    __syncthreads();
    for (int i = threadIdx.x; i < 16 * 16 * HH; i += 256) {
        int bb = i / (16 * HH), rj = i % (16 * HH);
        int r = rj / HH, j = rj % HH;
        out[(size_t)(b0 + bb) * (TT * HH) + (t0 + r) * HH + j] = tile[r * (16 * HH) + bb * HH + j];
    }
}

extern "C" void kernel_launch(void* const* d_in, const int* in_sizes, int n_in,
                              void* d_out, int out_size, void* d_ws, size_t ws_size,
                              hipStream_t stream) {
    const float* x    = (const float*)d_in[0];
    const float* h0   = (const float*)d_in[1];
    const float* Wi   = (const float*)d_in[2];
    const float* Wh   = (const float*)d_in[3];
    const float* bias = (const float*)d_in[4];
    float* out = (float*)d_out;

    char* w = (char*)d_ws;
    float* wsf = (float*)w;
    int* wsi = (int*)w;
    unsigned* amax = (unsigned*)w;
    float* xw = (float*)(w + WS_XW_OFF);

    hipMemsetAsync(d_ws, 0, 64, stream);
    int n = in_sizes[0];
    k_amax<<<2048, 256, 0, stream>>>(x, n / 4, amax);
    k_prep<<<1, 256, 0, stream>>>(Wi, Wh, bias, h0, wsf, wsi);
    k_xw<<<(BB * TT) / 256, 256, 0, stream>>>(x, wsf, wsi, xw);
    k_rnn<<<1, 1024, 0, stream>>>(h0, wsf, wsi, xw);
    k_tr<<<dim3(TT / 16, BB / 16), 256, 0, stream>>>(xw, out);
}

// Round 4
// 4575.963 us; speedup vs baseline: 1.2096x; 1.2096x over previous
//
#include <hip/hip_runtime.h>
#include <math.h>

// Problem constants: B=512, T=2048, D=10, H=20
#define BB 512
#define TT 2048
#define DD 10
#define HH 20
#define BH (BB*HH)          // 10240 elements per timestep

// ws layout (word indices from base)
#define WS_AMAX     0
#define WS_PROD_XWI 4
#define WS_INV_SX   5
#define WS_S_H0     6
#define WS_INV_SH0  7
#define WS_S_WH     8
#define WS_BQ       16
#define WS_WIP      40
#define WS_WHP      104
#define WS_XW_OFF   4096     // byte offset of xW / out_t buffer: [T][B][H] floats (84 MB)

// LDS-only barrier: never drains vmcnt (prefetch loads / output stores stay in flight)
#define BAR() asm volatile("s_waitcnt lgkmcnt(0)\n\ts_barrier" ::: "memory")

__device__ __forceinline__ int dot4(int a, int b, int c) {
    return __builtin_amdgcn_sdot4(a, b, c, false);
}

// scale = exp2(ceil(log2(max(m,1e-10))))/128 via exponent bits (exact, branchless)
__device__ __forceinline__ void p2s(float m, float* s, float* is) {
    m = fmaxf(m, 1e-10f);
    unsigned u = __float_as_uint(m);
    int k = (int)(u >> 23) - 127 + ((u & 0x7fffffu) ? 1 : 0);  // ceil(log2(m))
    *s  = __uint_as_float((unsigned)(k + 120) << 23);           // 2^(k-7)
    *is = __uint_as_float((unsigned)(134 - k) << 23);           // 2^(7-k)
}

__device__ __forceinline__ float fmed3(float a, float b, float c) {
    return __builtin_amdgcn_fmed3f(a, b, c);
}

__device__ __forceinline__ int qlevel(float v, float inv) {
    return (int)fmed3(rintf(v * inv), -128.f, 127.f);
}

__device__ __forceinline__ int pack4(int a, int b, int c, int d) {
    return (a & 255) | ((b & 255) << 8) | ((c & 255) << 16) | ((d & 255) << 24);
}

// monotone float<->uint encoding: order-preserving for all finite floats
__device__ __forceinline__ unsigned fenc(float x) {
    unsigned u = __float_as_uint(x);
    return u ^ (unsigned)(((int)u >> 31) | 0x80000000);
}
__device__ __forceinline__ float fdec(unsigned e) {
    unsigned mask = (~(unsigned)((int)e >> 31)) | 0x80000000u;
    return __uint_as_float(e ^ mask);
}

__device__ __forceinline__ unsigned umx(unsigned a, unsigned b) { return a > b ? a : b; }

// wave64 umax via DPP (VALU only, no LDS): lane63 holds the full max
__device__ __forceinline__ unsigned wave_umax(unsigned m) {
    unsigned t;
    t = (unsigned)__builtin_amdgcn_update_dpp(0, (int)m, 0x111, 0xf, 0xf, true); m = umx(m, t); // shr1
    t = (unsigned)__builtin_amdgcn_update_dpp(0, (int)m, 0x112, 0xf, 0xf, true); m = umx(m, t); // shr2
    t = (unsigned)__builtin_amdgcn_update_dpp(0, (int)m, 0x114, 0xf, 0xf, true); m = umx(m, t); // shr4
    t = (unsigned)__builtin_amdgcn_update_dpp(0, (int)m, 0x118, 0xf, 0xf, true); m = umx(m, t); // shr8
    t = (unsigned)__builtin_amdgcn_update_dpp(0, (int)m, 0x142, 0xa, 0xf, true); m = umx(m, t); // bcast15
    t = (unsigned)__builtin_amdgcn_update_dpp(0, (int)m, 0x143, 0xc, 0xf, true); m = umx(m, t); // bcast31
    return m;
}

// umax over each 16-lane row (cyclic): every lane gets the row max
__device__ __forceinline__ unsigned row_umax(unsigned m) {
    unsigned t;
    t = (unsigned)__builtin_amdgcn_update_dpp(0, (int)m, 0x121, 0xf, 0xf, true); m = umx(m, t); // ror1
    t = (unsigned)__builtin_amdgcn_update_dpp(0, (int)m, 0x122, 0xf, 0xf, true); m = umx(m, t); // ror2
    t = (unsigned)__builtin_amdgcn_update_dpp(0, (int)m, 0x124, 0xf, 0xf, true); m = umx(m, t); // ror4
    t = (unsigned)__builtin_amdgcn_update_dpp(0, (int)m, 0x128, 0xf, 0xf, true); m = umx(m, t); // ror8
    return m;
}

// pair (lanes 2k,2k+1) h-level merge: 3 quad_perm DPP + byte splices -> hd[5]
__device__ __forceinline__ void mk_hd(int PA, int PB, int PC, bool isLo, int* hd) {
    int QA = __builtin_amdgcn_update_dpp(0, PA, 0xB1, 0xf, 0xf, true); // quad_perm [1,0,3,2]
    int QB = __builtin_amdgcn_update_dpp(0, PB, 0xB1, 0xf, 0xf, true);
    int QC = __builtin_amdgcn_update_dpp(0, PC, 0xB1, 0xf, 0xf, true);
    int XA = isLo ? PA : QA, XB = isLo ? PB : QB, XC = isLo ? PC : QC;
    int YA = isLo ? QA : PA, YB = isLo ? QB : PB, YC = isLo ? QC : PC;
    hd[0] = XA; hd[1] = XB;
    hd[2] = (XC & 0xFFFF) | (YA << 16);
    hd[3] = (int)((unsigned)YA >> 16) | (YB << 16);
    hd[4] = (int)((unsigned)YB >> 16) | (YC << 16);
}

// ---------------- kernel 1: maxabs(x) grid reduction -------------------------
__global__ void k_amax(const float* __restrict__ x, int n4, unsigned* amax) {
    int g = blockIdx.x * blockDim.x + threadIdx.x;
    int stride = gridDim.x * blockDim.x;
    const float4* xv = (const float4*)x;
    float m = 0.f;
    for (int i = g; i < n4; i += stride) {
        float4 v = xv[i];
        m = fmaxf(m, fmaxf(fmaxf(fabsf(v.x), fabsf(v.y)), fmaxf(fabsf(v.z), fabsf(v.w))));
    }
#pragma unroll
    for (int off = 32; off; off >>= 1) m = fmaxf(m, __shfl_xor(m, off, 64));
    if ((threadIdx.x & 63) == 0) atomicMax(amax, __float_as_uint(m));
}

// ---------------- kernel 2: scales + weight quant/pack -----------------------
__device__ float bmaxabs(const float* p, int n, float* red, int tid) {
    float m = 0.f;
    for (int i = tid; i < n; i += 256) m = fmaxf(m, fabsf(p[i]));
    red[tid] = m; __syncthreads();
    for (int s = 128; s; s >>= 1) {
        if (tid < s) red[tid] = fmaxf(red[tid], red[tid + s]);
        __syncthreads();
    }
    m = red[0]; __syncthreads();
    return m;
}

__global__ void k_prep(const float* __restrict__ Wi, const float* __restrict__ Wh,
                       const float* __restrict__ bias, const float* __restrict__ h0,
                       float* wsf, int* wsi) {
    __shared__ float red[256];
    __shared__ float hdr[4];
    int tid = threadIdx.x;
    float mwi = bmaxabs(Wi, HH * DD, red, tid);
    float mwh = bmaxabs(Wh, HH * HH, red, tid);
    float mb  = bmaxabs(bias, HH, red, tid);
    float mh0 = bmaxabs(h0, BH, red, tid);
    if (tid == 0) {
        float mx = __uint_as_float(((unsigned*)wsf)[WS_AMAX]);
        float sx, isx, swi, iswi, swh, iswh, sb, isb, sh0, ish0;
        p2s(mx,  &sx,  &isx);
        p2s(mwi, &swi, &iswi);
        p2s(mwh, &swh, &iswh);
        p2s(mb,  &sb,  &isb);
        p2s(mh0, &sh0, &ish0);
        wsf[WS_PROD_XWI] = sx * swi;
        wsf[WS_INV_SX]   = isx;
        wsf[WS_S_H0]     = sh0;
        wsf[WS_INV_SH0]  = ish0;
        wsf[WS_S_WH]     = swh;
        hdr[0] = iswi; hdr[1] = iswh; hdr[2] = sb; hdr[3] = isb;
    }
    __syncthreads();
    if (tid < HH) {
        float iswi = hdr[0], iswh = hdr[1], sb = hdr[2], isb = hdr[3];
        int lv[20];
#pragma unroll
        for (int d = 0; d < DD; ++d) lv[d] = qlevel(Wi[tid * DD + d], iswi);
        lv[10] = 0; lv[11] = 0;
#pragma unroll
        for (int k = 0; k < 3; ++k)
            wsi[WS_WIP + tid * 3 + k] = pack4(lv[4*k], lv[4*k+1], lv[4*k+2], lv[4*k+3]);
#pragma unroll
        for (int k = 0; k < HH; ++k) lv[k] = qlevel(Wh[tid * HH + k], iswh);
#pragma unroll
        for (int k = 0; k < 5; ++k)
            wsi[WS_WHP + tid * 5 + k] = pack4(lv[4*k], lv[4*k+1], lv[4*k+2], lv[4*k+3]);
        wsf[WS_BQ + tid] = (float)qlevel(bias[tid], isb) * sb;
    }
}

// ---------------- kernel 3: xW[t][b][j] = quant(x)·Wi_q + bq -----------------
__global__ __launch_bounds__(256) void k_xw(const float* __restrict__ x,
                                            const float* __restrict__ wsf,
                                            const int* __restrict__ wsi,
                                            float* __restrict__ xw) {
    int g = blockIdx.x * 256 + threadIdx.x;
    int b = g & (BB - 1);
    int t = g >> 9;
    float isx  = wsf[WS_INV_SX];
    float prod = wsf[WS_PROD_XWI];
    const float2* xp = (const float2*)(x + ((size_t)b * TT + t) * DD);
    float xv[10];
#pragma unroll
    for (int k = 0; k < 5; ++k) { float2 v = xp[k]; xv[2*k] = v.x; xv[2*k+1] = v.y; }
    int lv[12];
#pragma unroll
    for (int d = 0; d < DD; ++d) lv[d] = qlevel(xv[d], isx);
    lv[10] = 0; lv[11] = 0;
    int xpk[3];
#pragma unroll
    for (int k = 0; k < 3; ++k) xpk[k] = pack4(lv[4*k], lv[4*k+1], lv[4*k+2], lv[4*k+3]);
    float res[20];
#pragma unroll
    for (int j = 0; j < HH; ++j) {
        int ai = 0;
#pragma unroll
        for (int k = 0; k < 3; ++k) ai = dot4(xpk[k], wsi[WS_WIP + j * 3 + k], ai);
        res[j] = (float)ai * prod + wsf[WS_BQ + j];
    }
    float4* op = (float4*)(xw + (size_t)t * BH + b * HH);
#pragma unroll
    for (int k = 0; k < 5; ++k)
        op[k] = make_float4(res[4*k], res[4*k+1], res[4*k+2], res[4*k+3]);
}

// ---------------- kernel 4: serial recurrence, 1 workgroup -------------------
// thread = (b, jhalf). __launch_bounds__(1024,4): 4 waves/EU = our exactly-one
// block -> 128-VGPR budget so whp[50] (packed Wh) stays IN REGISTERS (at the
// default budget the compiler allocated 52 VGPRs and spilled whp to scratch —
// ~50 scratch reloads/thread/step dominated rounds 1-3 at a constant ~5.2 ms).
// Per step: dot4 matmul -> DPP wave max -> B1 -> waves 0-3 only: cross-wave
// reduce + scales + exact-tanhf LUT {level, float out} -> B2 -> all: ds_read_b64
// gather -> store + DPP pair exchange. 2 LDS-only barriers.
__global__ __launch_bounds__(1024, 4) void k_rnn(const float* __restrict__ h0,
                                                 const float* __restrict__ wsf,
                                                 const int* __restrict__ wsi,
                                                 float* __restrict__ xw) {
    __shared__ uint2 wred[16];
    __shared__ float bc[4];
    __shared__ int2 lut[256];
    const int tid = threadIdx.x;
    const int b = tid >> 1;
    const int jb = (tid & 1) * 10;
    const bool isLo = (tid & 1) == 0;
    const float s_wh = wsf[WS_S_WH];
    float sprod = wsf[WS_S_H0] * s_wh;

    int whp[50];
#pragma unroll
    for (int jj = 0; jj < 10; ++jj)
#pragma unroll
        for (int k = 0; k < 5; ++k)
            whp[jj * 5 + k] = wsi[WS_WHP + (jb + jj) * 5 + k];

    int hd[5];
    {   // h0 -> levels -> pack -> pair exchange
        float ish0 = wsf[WS_INV_SH0];
        const float2* hp = (const float2*)(h0 + b * HH + jb);
        int lv[10];
#pragma unroll
        for (int k = 0; k < 5; ++k) {
            float2 v = hp[k];
            lv[2*k]   = qlevel(v.x, ish0);
            lv[2*k+1] = qlevel(v.y, ish0);
        }
        mk_hd(pack4(lv[0], lv[1], lv[2], lv[3]),
              pack4(lv[4], lv[5], lv[6], lv[7]),
              (lv[8] & 255) | ((lv[9] & 255) << 8), isLo, hd);
    }
    float xwA[10];
    {
        const float2* p = (const float2*)(xw + b * HH + jb);
#pragma unroll
        for (int k = 0; k < 5; ++k) { float2 v = p[k]; xwA[2*k] = v.x; xwA[2*k+1] = v.y; }
    }
    const float2* pf = (const float2*)(xw + (size_t)BH + b * HH + jb);  // row t+1
    float2*       po = (float2*)(xw + b * HH + jb);                      // row t

    for (int t = 0; t < TT; ++t) {
        float xwB[10];
        if (t + 1 < TT) {   // wave-uniform; loads stay in flight across barriers
#pragma unroll
            for (int k = 0; k < 5; ++k) { float2 v = pf[k]; xwB[2*k] = v.x; xwB[2*k+1] = v.y; }
        }
        float acc[10];
#pragma unroll
        for (int jj = 0; jj < 10; ++jj) {
            int ai = 0;
#pragma unroll
            for (int k = 0; k < 5; ++k) ai = dot4(hd[k], whp[jj * 5 + k], ai);
            acc[jj] = fmaf((float)ai, sprod, xwA[jj]);   // exact: |ai| < 2^24, pow2 scale
        }
        // fold 10 -> (max, min), then monotone-uint DPP wave reduce
        float mx = acc[0], mn = acc[0];
#pragma unroll
        for (int jj = 1; jj < 10; ++jj) { mx = fmaxf(mx, acc[jj]); mn = fminf(mn, acc[jj]); }
        unsigned ea = wave_umax(fenc(mx));    // max(acc)
        unsigned eb = wave_umax(fenc(-mn));   // max(-acc)
        if ((tid & 63) == 63) wred[tid >> 6] = make_uint2(ea, eb);
        BAR();   // B1
        float isa, sh;
        if (tid < 256) {   // waves 0-3 only: cross-wave reduce + scales + LUT
            uint2 wp = wred[tid & 15];
            float ma = fdec(row_umax(wp.x));
            float nm = fdec(row_umax(wp.y));
            float sa; p2s(fmaxf(ma, nm), &sa, &isa);
            float lp = fmed3(rintf(ma * isa), -128.f, 127.f);
            float ln = fmed3(rintf(-nm * isa), -128.f, 127.f);
            float mlvl = fmaxf(fabsf(lp), fabsf(ln));   // max |acc_q| (clip asym incl.)
            float mh = tanhf(mlvl * sa);                // max |h_new| (tanh monotone)
            float ish; p2s(mh, &sh, &ish);
            sprod = sh * s_wh;
            float tq = tanhf((float)(tid - 128) * sa);  // exact LUT entry
            int lv = (int)fmed3(rintf(tq * ish), -128.f, 127.f);
            lut[tid] = make_int2(lv, __float_as_int((float)lv * sh));
            if (tid == 0) { bc[0] = isa; bc[1] = sh; bc[2] = sprod; }
        }
        BAR();   // B2
        if (tid >= 256) { isa = bc[0]; sh = bc[1]; sprod = bc[2]; }
        int ql[10];
#pragma unroll
        for (int k = 0; k < 5; ++k) {   // gather {level, out-float}, store pair
            int qa = (int)fmed3(rintf(acc[2*k]   * isa), -128.f, 127.f);
            int qb = (int)fmed3(rintf(acc[2*k+1] * isa), -128.f, 127.f);
            int2 ea2 = lut[qa + 128];
            int2 eb2 = lut[qb + 128];
            ql[2*k]   = ea2.x;
            ql[2*k+1] = eb2.x;
            po[k] = make_float2(__int_as_float(ea2.y), __int_as_float(eb2.y));
        }
        mk_hd(pack4(ql[0], ql[1], ql[2], ql[3]),
              pack4(ql[4], ql[5], ql[6], ql[7]),
              (ql[8] & 255) | ((ql[9] & 255) << 8), isLo, hd);
#pragma unroll
        for (int jj = 0; jj < 10; ++jj) xwA[jj] = xwB[jj];
        pf += BH / 2;
        po += BH / 2;
    }
}

// ---------------- kernel 5: transpose [T][B][H] -> [B][T][H] -----------------
__global__ __launch_bounds__(256) void k_tr(const float* __restrict__ src, float* __restrict__ out) {
    __shared__ float tile[16 * 16 * HH];   // 20 KB
    int t0 = blockIdx.x * 16, b0 = blockIdx.y * 16;
    for (int i = threadIdx.x; i < 16 * 16 * HH; i += 256) {
        int r = i / (16 * HH), c = i % (16 * HH);
        tile[i] = src[(size_t)(t0 + r) * BH + b0 * HH + c];
    }
    __syncthreads();
    for (int i = threadIdx.x; i < 16 * 16 * HH; i += 256) {
        int bb = i / (16 * HH), rj = i % (16 * HH);
        int r = rj / HH, j = rj % HH;
        out[(size_t)(b0 + bb) * (TT * HH) + (t0 + r) * HH + j] = tile[r * (16 * HH) + bb * HH + j];
    }
}

extern "C" void kernel_launch(void* const* d_in, const int* in_sizes, int n_in,
                              void* d_out, int out_size, void* d_ws, size_t ws_size,
                              hipStream_t stream) {
    const float* x    = (const float*)d_in[0];
    const float* h0   = (const float*)d_in[1];
    const float* Wi   = (const float*)d_in[2];
    const float* Wh   = (const float*)d_in[3];
    const float* bias = (const float*)d_in[4];
    float* out = (float*)d_out;

    char* w = (char*)d_ws;
    float* wsf = (float*)w;
    int* wsi = (int*)w;
    unsigned* amax = (unsigned*)w;
    float* xw = (float*)(w + WS_XW_OFF);

    hipMemsetAsync(d_ws, 0, 64, stream);
    int n = in_sizes[0];
    k_amax<<<2048, 256, 0, stream>>>(x, n / 4, amax);
    k_prep<<<1, 256, 0, stream>>>(Wi, Wh, bias, h0, wsf, wsi);
    k_xw<<<(BB * TT) / 256, 256, 0, stream>>>(x, wsf, wsi, xw);
    k_rnn<<<1, 1024, 0, stream>>>(h0, wsf, wsi, xw);
    k_tr<<<dim3(TT / 16, BB / 16), 256, 0, stream>>>(xw, out);
}